// Round 1
// baseline (540.765 us; speedup 1.0000x reference)
//
#include <hip/hip_runtime.h>

// MaxPool2d k=2 s=2 on (32, 64, 224, 224) fp32 -> (32, 64, 112, 112).
// Memory-bound: 411 MB read + 103 MB write, every input byte used exactly once.
// Each thread: 2x float4 input loads (a 4-wide x 2-high patch = two 2x2 windows),
// 3 max-trees, one float2 store. Fully coalesced, 16B/lane loads.

#define H_IN 224
#define W_IN 224
#define H_OUT 112
#define W_OUT 112
#define W_PAIRS 56              // W_OUT / 2 == W_IN / 4
#define PLANE_F4 (H_IN * W_IN / 4)   // 12544 float4 per input plane
#define PLANE_F2 (H_OUT * W_OUT / 2) // 6272 float2 per output plane

__global__ __launch_bounds__(256) void maxpool2d_kernel(
    const float4* __restrict__ in4, float2* __restrict__ out2) {
    int t = blockIdx.x * blockDim.x + threadIdx.x;

    int col_pair = t % W_PAIRS;          // which float4 within the input row
    int tmp      = t / W_PAIRS;
    int row      = tmp % H_OUT;          // output row
    int plane    = tmp / H_OUT;          // n*C + c

    int base4 = plane * PLANE_F4 + row * (2 * W_PAIRS) + col_pair; // row*112
    float4 a = in4[base4];               // input row 2*row
    float4 b = in4[base4 + W_PAIRS];     // input row 2*row + 1

    float2 r;
    r.x = fmaxf(fmaxf(a.x, a.y), fmaxf(b.x, b.y));
    r.y = fmaxf(fmaxf(a.z, a.w), fmaxf(b.z, b.w));

    out2[plane * PLANE_F2 + row * W_PAIRS + col_pair] = r;
}

extern "C" void kernel_launch(void* const* d_in, const int* in_sizes, int n_in,
                              void* d_out, int out_size, void* d_ws, size_t ws_size,
                              hipStream_t stream) {
    const float4* in4 = (const float4*)d_in[0];
    float2* out2 = (float2*)d_out;

    // total output pairs = 32*64*112*56 = 12,845,056; /256 = 50176 blocks exactly
    int total_pairs = out_size / 2;
    int blocks = (total_pairs + 255) / 256;
    maxpool2d_kernel<<<blocks, 256, 0, stream>>>(in4, out2);
}